// Round 5
// baseline (35.368 us; speedup 1.0000x reference)
//
#include <hip/hip_runtime.h>
#include <math.h>

namespace {

constexpr int NB = 8;     // batch
constexpr int NS = 48;    // samples
constexpr int NA = 8192;  // atoms
constexpr int TPB = 512;  // 8 waves/block; 2 blocks/CU resident
constexpr int NBS = NB * NS;  // 384 blocks, one per (b,s)
constexpr int NW = TPB / 64;

// Single self-sufficient kernel: each block owns one (b,s), covers all 8192
// atoms, computes BOTH the per-sample sums (13) and the per-b stats (6)
// redundantly from the same loaded data, eigen-solves its own 3x3, and
// contributes one atomicAdd to out[0]. No inter-block dependency -> no fence,
// no second dispatch. d_out is zeroed by a 4-byte memset node each launch.

__global__ __launch_bounds__(TPB, 4) void loss_kernel(
    const float* __restrict__ pred, const float* __restrict__ truec,
    const int* __restrict__ mask, const int* __restrict__ dna,
    const int* __restrict__ rna, const int* __restrict__ lig,
    const float* __restrict__ scale, float* __restrict__ out) {
  const int bs = blockIdx.x;
  const int b = bs / NS;
  const float* p = pred + (size_t)bs * NA * 3;
  const float* t = truec + (size_t)b * NA * 3;
  const int mbase = b * NA;

  float acc[13];
#pragma unroll
  for (int k = 0; k < 13; ++k) acc[k] = 0.f;
  float accb[6];
#pragma unroll
  for (int k = 0; k < 6; ++k) accb[k] = 0.f;

  auto atom = [&](float mf, float w, float p0, float p1, float p2, float t0,
                  float t1, float t2) {
    const float wp0 = w * p0, wp1 = w * p1, wp2 = w * p2;
    acc[0] += wp0 * p0 + wp1 * p1 + wp2 * p2;
    acc[1] += wp0;
    acc[2] += wp1;
    acc[3] += wp2;
    acc[4] += wp0 * t0;
    acc[5] += wp0 * t1;
    acc[6] += wp0 * t2;
    acc[7] += wp1 * t0;
    acc[8] += wp1 * t1;
    acc[9] += wp1 * t2;
    acc[10] += wp2 * t0;
    acc[11] += wp2 * t1;
    acc[12] += wp2 * t2;
    // per-b stats from the same data (free traffic-wise)
    accb[0] += w;
    accb[1] += w * t0;
    accb[2] += w * t1;
    accb[3] += w * t2;
    accb[4] += w * (t0 * t0 + t1 * t1 + t2 * t2);
    accb[5] += mf;
  };
  auto wgt = [](int m, int d, int r, int l) {
    return (float)((1 + 5 * (d + r) + 10 * l) * m);
  };

#pragma unroll
  for (int it = 0; it < NA / (TPB * 4); ++it) {  // 4 iters of 4 atoms
    const int n0 = it * (TPB * 4) + threadIdx.x * 4;
    const float4 pa = *(const float4*)(p + 3 * n0);
    const float4 pb = *(const float4*)(p + 3 * n0 + 4);
    const float4 pc = *(const float4*)(p + 3 * n0 + 8);
    const float4 ta = *(const float4*)(t + 3 * n0);
    const float4 tb = *(const float4*)(t + 3 * n0 + 4);
    const float4 tc = *(const float4*)(t + 3 * n0 + 8);
    const int4 mk = *(const int4*)(mask + mbase + n0);
    const int4 dn = *(const int4*)(dna + mbase + n0);
    const int4 rn = *(const int4*)(rna + mbase + n0);
    const int4 lg = *(const int4*)(lig + mbase + n0);

    atom((float)mk.x, wgt(mk.x, dn.x, rn.x, lg.x), pa.x, pa.y, pa.z, ta.x, ta.y, ta.z);
    atom((float)mk.y, wgt(mk.y, dn.y, rn.y, lg.y), pa.w, pb.x, pb.y, ta.w, tb.x, tb.y);
    atom((float)mk.z, wgt(mk.z, dn.z, rn.z, lg.z), pb.z, pb.w, pc.x, tb.z, tb.w, tc.x);
    atom((float)mk.w, wgt(mk.w, dn.w, rn.w, lg.w), pc.y, pc.z, pc.w, tc.y, tc.z, tc.w);
  }

  // block-reduce 19 values: wave shfl-reduce -> LDS -> column sums
  __shared__ float lds[NW][19];
  __shared__ float sums[19];
  const int lane = threadIdx.x & 63;
  const int wave = threadIdx.x >> 6;
#pragma unroll
  for (int k = 0; k < 19; ++k) {
    float x = (k < 13) ? acc[k] : accb[k - 13];
#pragma unroll
    for (int off = 32; off; off >>= 1) x += __shfl_xor(x, off, 64);
    if (lane == 0) lds[wave][k] = x;
  }
  __syncthreads();
  if ((int)threadIdx.x < 19) {
    float s = 0.f;
#pragma unroll
    for (int w = 0; w < NW; ++w) s += lds[w][threadIdx.x];
    sums[threadIdx.x] = s;
  }
  __syncthreads();

  if (threadIdx.x == 0) {
    const double wsum = (double)sums[13];
    const double St[3] = {(double)sums[14], (double)sums[15], (double)sums[16]};
    const double stt = (double)sums[17];
    const double msum = (double)sums[18];

    const double spp = (double)sums[0];
    const double Sp[3] = {(double)sums[1], (double)sums[2], (double)sums[3]};
    const double inv = 1.0 / wsum;

    double H[3][3];
#pragma unroll
    for (int i = 0; i < 3; ++i)
#pragma unroll
      for (int j = 0; j < 3; ++j)
        H[i][j] = (double)sums[4 + 3 * i + j] - Sp[i] * St[j] * inv;

    const double Sq = spp - (Sp[0] * Sp[0] + Sp[1] * Sp[1] + Sp[2] * Sp[2]) * inv;
    const double Sy = stt - (St[0] * St[0] + St[1] * St[1] + St[2] * St[2]) * inv;

    double K[3][3];
#pragma unroll
    for (int i = 0; i < 3; ++i)
#pragma unroll
      for (int j = 0; j < 3; ++j)
        K[i][j] = H[0][i] * H[0][j] + H[1][i] * H[1][j] + H[2][i] * H[2][j];

    const double q = (K[0][0] + K[1][1] + K[2][2]) / 3.0;
    const double p1 = K[0][1] * K[0][1] + K[0][2] * K[0][2] + K[1][2] * K[1][2];
    const double a0 = K[0][0] - q, a1 = K[1][1] - q, a2 = K[2][2] - q;
    const double p2 = a0 * a0 + a1 * a1 + a2 * a2 + 2.0 * p1;
    double e1, e2, e3;
    if (p2 <= 1e-300) {
      e1 = e2 = e3 = q;
    } else {
      const double pp = sqrt(p2 / 6.0);
      const double ip = 1.0 / pp;
      const double B00 = a0 * ip, B11 = a1 * ip, B22 = a2 * ip;
      const double B01 = K[0][1] * ip, B02 = K[0][2] * ip, B12 = K[1][2] * ip;
      double r = 0.5 * (B00 * (B11 * B22 - B12 * B12) - B01 * (B01 * B22 - B12 * B02) +
                        B02 * (B01 * B12 - B11 * B02));
      float rf = fminf(1.0f, fmaxf(-1.0f, (float)r));
      const float phi = acosf(rf) * (1.0f / 3.0f);
      e1 = q + 2.0 * pp * (double)cosf(phi);
      e3 = q + 2.0 * pp * (double)cosf(phi + 2.0943951023931953f);
      e2 = 3.0 * q - e1 - e3;
    }
    const double s1 = sqrt(fmax(e1, 0.0));
    const double s2 = sqrt(fmax(e2, 0.0));
    const double s3 = sqrt(fmax(e3, 0.0));

    const double detH =
        H[0][0] * (H[1][1] * H[2][2] - H[1][2] * H[2][1]) -
        H[0][1] * (H[1][0] * H[2][2] - H[1][2] * H[2][0]) +
        H[0][2] * (H[1][0] * H[2][1] - H[1][1] * H[2][0]);
    const double d = (detH > 0.0) ? 1.0 : ((detH < 0.0) ? -1.0 : 0.0);

    const double cost = Sq + Sy - 2.0 * (s1 + s2 + d * s3);
    const double contrib =
        cost / (msum + 1e-6) * (double)scale[bs] * (1.0 / (3.0 * (double)NS * (double)NB));
    atomicAdd(out, (float)contrib);  // device-scope, no fence needed
  }
}

}  // namespace

extern "C" void kernel_launch(void* const* d_in, const int* in_sizes, int n_in,
                              void* d_out, int out_size, void* d_ws, size_t ws_size,
                              hipStream_t stream) {
  const float* pred = (const float*)d_in[0];
  const float* truec = (const float*)d_in[1];
  const int* mask = (const int*)d_in[2];
  const int* dna = (const int*)d_in[3];
  const int* rna = (const int*)d_in[4];
  const int* lig = (const int*)d_in[5];
  const float* scale = (const float*)d_in[6];
  float* out = (float*)d_out;

  hipMemsetAsync(out, 0, sizeof(float), stream);
  loss_kernel<<<NBS, TPB, 0, stream>>>(pred, truec, mask, dna, rna, lig, scale, out);
}

// Round 6
// 33.798 us; speedup vs baseline: 1.0465x; 1.0465x over previous
//
#include <hip/hip_runtime.h>
#include <math.h>

namespace {

constexpr int NB = 8;     // batch
constexpr int NS = 48;    // samples
constexpr int NA = 8192;  // atoms
constexpr int TPB = 512;  // threads per block (8 waves)
constexpr int NW = TPB / 64;
constexpr int CH = 4;     // 2048-atom chunks per (b,s)
constexpr int SGRP = 4;   // samples per block
constexpr int NGRP = NS / SGRP;  // 12
constexpr int NBS = NB * NS;     // 384
constexpr int GRID = NB * CH * NGRP;  // 384 blocks

// ws layout (floats):
// [0 .. NBS*CH*16)      per-(b,s,chunk) partials, 13 used of 16: idx (bs*CH+c)*16
// [PBOFF .. +NB*CH*8)   per-(b,chunk) stats, 6 used of 8: idx (b*CH+c)*8
constexpr int PBOFF = NBS * CH * 16;  // 24576

// Kernel 1: s-tiled. Block = (b, chunk, sample-group). Loads true+masks for
// its 2048-atom chunk ONCE (regs), then accumulates 13 sums for 4 samples.
// Cuts L2-side traffic from 126 MB to ~59 MB vs the per-(b,s,chunk) layout.
__global__ __launch_bounds__(TPB) void stats_kernel(
    const float* __restrict__ pred, const float* __restrict__ truec,
    const int* __restrict__ mask, const int* __restrict__ dna,
    const int* __restrict__ rna, const int* __restrict__ lig,
    float* __restrict__ ws) {
  const int blk = blockIdx.x;
  const int b = blk / (CH * NGRP);
  const int rem = blk % (CH * NGRP);
  const int chunk = rem / NGRP;
  const int sgrp = rem % NGRP;
  const int bs0 = b * NS + sgrp * SGRP;  // first of 4 samples
  const bool isG0 = (sgrp == 0);

  const int n0 = chunk * 2048 + threadIdx.x * 4;  // 4 atoms per thread
  const int mbase = b * NA + n0;
  const float* t = truec + ((size_t)b * NA + n0) * 3;

  // --- load true + masks once ---
  const float4 ta = *(const float4*)(t);
  const float4 tb = *(const float4*)(t + 4);
  const float4 tc = *(const float4*)(t + 8);
  const int4 mk = *(const int4*)(mask + mbase);
  const int4 dn = *(const int4*)(dna + mbase);
  const int4 rn = *(const int4*)(rna + mbase);
  const int4 lg = *(const int4*)(lig + mbase);

  auto wgt = [](int m, int d, int r, int l) {
    return (float)((1 + 5 * (d + r) + 10 * l) * m);
  };
  const float w0 = wgt(mk.x, dn.x, rn.x, lg.x);
  const float w1 = wgt(mk.y, dn.y, rn.y, lg.y);
  const float w2 = wgt(mk.z, dn.z, rn.z, lg.z);
  const float w3 = wgt(mk.w, dn.w, rn.w, lg.w);

  float acc[SGRP][13];
#pragma unroll
  for (int sg = 0; sg < SGRP; ++sg)
#pragma unroll
    for (int k = 0; k < 13; ++k) acc[sg][k] = 0.f;

#pragma unroll
  for (int sg = 0; sg < SGRP; ++sg) {  // full unroll -> static acc indices
    const float* p = pred + ((size_t)(bs0 + sg) * NA + n0) * 3;
    const float4 pa = *(const float4*)(p);
    const float4 pb = *(const float4*)(p + 4);
    const float4 pc = *(const float4*)(p + 8);

    auto atom = [&](float w, float p0, float p1, float p2, float t0, float t1,
                    float t2) {
      const float wp0 = w * p0, wp1 = w * p1, wp2 = w * p2;
      acc[sg][0] += wp0 * p0 + wp1 * p1 + wp2 * p2;
      acc[sg][1] += wp0;
      acc[sg][2] += wp1;
      acc[sg][3] += wp2;
      acc[sg][4] += wp0 * t0;
      acc[sg][5] += wp0 * t1;
      acc[sg][6] += wp0 * t2;
      acc[sg][7] += wp1 * t0;
      acc[sg][8] += wp1 * t1;
      acc[sg][9] += wp1 * t2;
      acc[sg][10] += wp2 * t0;
      acc[sg][11] += wp2 * t1;
      acc[sg][12] += wp2 * t2;
    };
    atom(w0, pa.x, pa.y, pa.z, ta.x, ta.y, ta.z);
    atom(w1, pa.w, pb.x, pb.y, ta.w, tb.x, tb.y);
    atom(w2, pb.z, pb.w, pc.x, tb.z, tb.w, tc.x);
    atom(w3, pc.y, pc.z, pc.w, tc.y, tc.z, tc.w);
  }

  float accb[6];
  if (isG0) {  // per-b stats, data already in regs (32 of 384 blocks)
    accb[0] = w0 + w1 + w2 + w3;
    accb[1] = w0 * ta.x + w1 * ta.w + w2 * tb.z + w3 * tc.y;
    accb[2] = w0 * ta.y + w1 * tb.x + w2 * tb.w + w3 * tc.z;
    accb[3] = w0 * ta.z + w1 * tb.y + w2 * tc.x + w3 * tc.w;
    accb[4] = w0 * (ta.x * ta.x + ta.y * ta.y + ta.z * ta.z) +
              w1 * (ta.w * ta.w + tb.x * tb.x + tb.y * tb.y) +
              w2 * (tb.z * tb.z + tb.w * tb.w + tc.x * tc.x) +
              w3 * (tc.y * tc.y + tc.z * tc.z + tc.w * tc.w);
    accb[5] = (float)(mk.x + mk.y + mk.z + mk.w);
  }

  // --- block reduce: 52 (or 58) values ---
  __shared__ float lds[NW][58];
  const int lane = threadIdx.x & 63;
  const int wave = threadIdx.x >> 6;
#pragma unroll
  for (int sg = 0; sg < SGRP; ++sg)
#pragma unroll
    for (int k = 0; k < 13; ++k) {
      float x = acc[sg][k];
#pragma unroll
      for (int off = 32; off; off >>= 1) x += __shfl_xor(x, off, 64);
      if (lane == 0) lds[wave][sg * 13 + k] = x;
    }
  if (isG0) {
#pragma unroll
    for (int k = 0; k < 6; ++k) {
      float x = accb[k];
#pragma unroll
      for (int off = 32; off; off >>= 1) x += __shfl_xor(x, off, 64);
      if (lane == 0) lds[wave][52 + k] = x;
    }
  }
  __syncthreads();

  const int nvals = isG0 ? 58 : 52;
  const int tid = threadIdx.x;
  if (tid < nvals) {
    float s = 0.f;
#pragma unroll
    for (int w = 0; w < NW; ++w) s += lds[w][tid];
    if (tid < 52) {
      const int sg = tid / 13, j = tid % 13;
      ws[(size_t)((bs0 + sg) * CH + chunk) * 16 + j] = s;
    } else {
      ws[PBOFF + (size_t)(b * CH + chunk) * 8 + (tid - 52)] = s;
    }
  }
}

__global__ __launch_bounds__(NBS) void final_kernel(const float* __restrict__ ws,
                                                    const float* __restrict__ scale,
                                                    float* __restrict__ out) {
  const int tid = threadIdx.x;  // 0..383, tid = bs = b*NS + s
  __shared__ double bv[NB][6];

  if (tid < NB) {
    double s[6] = {0, 0, 0, 0, 0, 0};
    for (int c = 0; c < CH; ++c) {
      const float* q = ws + PBOFF + (tid * CH + c) * 8;
#pragma unroll
      for (int k = 0; k < 6; ++k) s[k] += (double)q[k];
    }
#pragma unroll
    for (int k = 0; k < 6; ++k) bv[tid][k] = s[k];
  }
  __syncthreads();

  const int b = tid / NS;
  double sums[13];
#pragma unroll
  for (int k = 0; k < 13; ++k) sums[k] = 0.0;
  for (int c = 0; c < CH; ++c) {
    const float4* q4 = (const float4*)(ws + (size_t)(tid * CH + c) * 16);
    const float4 qa = q4[0], qb = q4[1], qc = q4[2], qd = q4[3];
    sums[0] += (double)qa.x;  sums[1] += (double)qa.y;
    sums[2] += (double)qa.z;  sums[3] += (double)qa.w;
    sums[4] += (double)qb.x;  sums[5] += (double)qb.y;
    sums[6] += (double)qb.z;  sums[7] += (double)qb.w;
    sums[8] += (double)qc.x;  sums[9] += (double)qc.y;
    sums[10] += (double)qc.z; sums[11] += (double)qc.w;
    sums[12] += (double)qd.x;
  }

  const double wsum = bv[b][0];
  const double St[3] = {bv[b][1], bv[b][2], bv[b][3]};
  const double stt = bv[b][4];
  const double msum = bv[b][5];

  const double spp = sums[0];
  const double Sp[3] = {sums[1], sums[2], sums[3]};
  const double inv = 1.0 / wsum;

  double H[3][3];
#pragma unroll
  for (int i = 0; i < 3; ++i)
#pragma unroll
    for (int j = 0; j < 3; ++j) H[i][j] = sums[4 + 3 * i + j] - Sp[i] * St[j] * inv;

  const double Sq = spp - (Sp[0] * Sp[0] + Sp[1] * Sp[1] + Sp[2] * Sp[2]) * inv;
  const double Sy = stt - (St[0] * St[0] + St[1] * St[1] + St[2] * St[2]) * inv;

  double K[3][3];
#pragma unroll
  for (int i = 0; i < 3; ++i)
#pragma unroll
    for (int j = 0; j < 3; ++j)
      K[i][j] = H[0][i] * H[0][j] + H[1][i] * H[1][j] + H[2][i] * H[2][j];

  const double q = (K[0][0] + K[1][1] + K[2][2]) / 3.0;
  const double p1 = K[0][1] * K[0][1] + K[0][2] * K[0][2] + K[1][2] * K[1][2];
  const double a0 = K[0][0] - q, a1 = K[1][1] - q, a2 = K[2][2] - q;
  const double p2 = a0 * a0 + a1 * a1 + a2 * a2 + 2.0 * p1;
  double e1, e2, e3;
  if (p2 <= 1e-300) {
    e1 = e2 = e3 = q;
  } else {
    const double pp = sqrt(p2 / 6.0);
    const double ip = 1.0 / pp;
    const double B00 = a0 * ip, B11 = a1 * ip, B22 = a2 * ip;
    const double B01 = K[0][1] * ip, B02 = K[0][2] * ip, B12 = K[1][2] * ip;
    double r = 0.5 * (B00 * (B11 * B22 - B12 * B12) - B01 * (B01 * B22 - B12 * B02) +
                      B02 * (B01 * B12 - B11 * B02));
    float rf = fminf(1.0f, fmaxf(-1.0f, (float)r));
    const float phi = acosf(rf) * (1.0f / 3.0f);
    e1 = q + 2.0 * pp * (double)cosf(phi);
    e3 = q + 2.0 * pp * (double)cosf(phi + 2.0943951023931953f);
    e2 = 3.0 * q - e1 - e3;
  }
  const double s1 = sqrt(fmax(e1, 0.0));
  const double s2 = sqrt(fmax(e2, 0.0));
  const double s3 = sqrt(fmax(e3, 0.0));

  const double detH =
      H[0][0] * (H[1][1] * H[2][2] - H[1][2] * H[2][1]) -
      H[0][1] * (H[1][0] * H[2][2] - H[1][2] * H[2][0]) +
      H[0][2] * (H[1][0] * H[2][1] - H[1][1] * H[2][0]);
  const double d = (detH > 0.0) ? 1.0 : ((detH < 0.0) ? -1.0 : 0.0);

  const double cost = Sq + Sy - 2.0 * (s1 + s2 + d * s3);
  double tot = cost / (msum + 1e-6) * (double)scale[tid];
  tot *= 1.0 / (3.0 * (double)NS * (double)NB);

#pragma unroll
  for (int off = 32; off; off >>= 1) tot += __shfl_xor(tot, off, 64);
  __shared__ double red[NBS / 64];
  if ((tid & 63) == 0) red[tid >> 6] = tot;
  __syncthreads();
  if (tid == 0) {
    double s = 0.0;
#pragma unroll
    for (int w = 0; w < NBS / 64; ++w) s += red[w];
    out[0] = (float)s;
  }
}

}  // namespace

extern "C" void kernel_launch(void* const* d_in, const int* in_sizes, int n_in,
                              void* d_out, int out_size, void* d_ws, size_t ws_size,
                              hipStream_t stream) {
  const float* pred = (const float*)d_in[0];
  const float* truec = (const float*)d_in[1];
  const int* mask = (const int*)d_in[2];
  const int* dna = (const int*)d_in[3];
  const int* rna = (const int*)d_in[4];
  const int* lig = (const int*)d_in[5];
  const float* scale = (const float*)d_in[6];
  float* ws = (float*)d_ws;
  float* out = (float*)d_out;

  stats_kernel<<<GRID, TPB, 0, stream>>>(pred, truec, mask, dna, rna, lig, ws);
  final_kernel<<<1, NBS, 0, stream>>>(ws, scale, out);
}

// Round 7
// 26.632 us; speedup vs baseline: 1.3280x; 1.2691x over previous
//
#include <hip/hip_runtime.h>
#include <math.h>

namespace {

constexpr int NB = 8;     // batch
constexpr int NS = 48;    // samples
constexpr int NA = 8192;  // atoms
constexpr int TPB = 256;  // threads per block (4 waves)
constexpr int NW = TPB / 64;
constexpr int CH = 4;     // 2048-atom chunks per (b,s)
constexpr int SGRP = 2;   // samples per block
constexpr int NGRP = NS / SGRP;       // 24
constexpr int NBS = NB * NS;          // 384
constexpr int GRID = NB * CH * NGRP;  // 768 blocks

// ws layout (floats):
// [0 .. NBS*CH*16)      per-(b,s,chunk) partials, 13 used of 16: idx (bs*CH+c)*16
// [PBOFF .. +NB*CH*8)   per-(b,chunk) stats, 6 used of 8: idx (b*CH+c)*8
constexpr int PBOFF = NBS * CH * 16;  // 24576

// Kernel 1: SGRP=2 tiling. Block = (b, chunk, sample-pair). Loads true+masks
// for its 2048-atom chunk once per iter, reuses for 2 samples. 8 atoms/thread
// -> 26-value reduce is ~16% overhead (R6's 52-val/4-atom was 43%).
__global__ __launch_bounds__(TPB) void stats_kernel(
    const float* __restrict__ pred, const float* __restrict__ truec,
    const int* __restrict__ mask, const int* __restrict__ dna,
    const int* __restrict__ rna, const int* __restrict__ lig,
    float* __restrict__ ws) {
  const int blk = blockIdx.x;
  const int sgrp = blk % NGRP;        // consecutive blocks share (b,chunk)
  const int bc = blk / NGRP;
  const int chunk = bc % CH;
  const int b = bc / CH;
  const int bs0 = b * NS + sgrp * SGRP;
  const bool isG0 = (sgrp == 0);

  const float* p0 = pred + (size_t)(bs0 + 0) * NA * 3;
  const float* p1 = pred + (size_t)(bs0 + 1) * NA * 3;
  const float* t = truec + (size_t)b * NA * 3;
  const int mbase = b * NA;

  float acc[SGRP][13];
#pragma unroll
  for (int sg = 0; sg < SGRP; ++sg)
#pragma unroll
    for (int k = 0; k < 13; ++k) acc[sg][k] = 0.f;
  float accb[6];
#pragma unroll
  for (int k = 0; k < 6; ++k) accb[k] = 0.f;

  auto wgt = [](int m, int d, int r, int l) {
    return (float)((1 + 5 * (d + r) + 10 * l) * m);
  };
  auto atomrow = [](float (&a)[13], float w, float q0, float q1, float q2,
                    float t0, float t1, float t2) {
    const float wq0 = w * q0, wq1 = w * q1, wq2 = w * q2;
    a[0] += wq0 * q0 + wq1 * q1 + wq2 * q2;
    a[1] += wq0;
    a[2] += wq1;
    a[3] += wq2;
    a[4] += wq0 * t0;
    a[5] += wq0 * t1;
    a[6] += wq0 * t2;
    a[7] += wq1 * t0;
    a[8] += wq1 * t1;
    a[9] += wq1 * t2;
    a[10] += wq2 * t0;
    a[11] += wq2 * t1;
    a[12] += wq2 * t2;
  };

#pragma unroll
  for (int it = 0; it < 2; ++it) {  // 2 iters x 4 atoms = 8 atoms/thread
    const int n0 = chunk * 2048 + it * (TPB * 4) + threadIdx.x * 4;
    const float4 ta = *(const float4*)(t + 3 * n0);
    const float4 tb = *(const float4*)(t + 3 * n0 + 4);
    const float4 tc = *(const float4*)(t + 3 * n0 + 8);
    const int4 mk = *(const int4*)(mask + mbase + n0);
    const int4 dn = *(const int4*)(dna + mbase + n0);
    const int4 rn = *(const int4*)(rna + mbase + n0);
    const int4 lg = *(const int4*)(lig + mbase + n0);

    const float w0 = wgt(mk.x, dn.x, rn.x, lg.x);
    const float w1 = wgt(mk.y, dn.y, rn.y, lg.y);
    const float w2 = wgt(mk.z, dn.z, rn.z, lg.z);
    const float w3 = wgt(mk.w, dn.w, rn.w, lg.w);

    {
      const float4 pa = *(const float4*)(p0 + 3 * n0);
      const float4 pb = *(const float4*)(p0 + 3 * n0 + 4);
      const float4 pc = *(const float4*)(p0 + 3 * n0 + 8);
      atomrow(acc[0], w0, pa.x, pa.y, pa.z, ta.x, ta.y, ta.z);
      atomrow(acc[0], w1, pa.w, pb.x, pb.y, ta.w, tb.x, tb.y);
      atomrow(acc[0], w2, pb.z, pb.w, pc.x, tb.z, tb.w, tc.x);
      atomrow(acc[0], w3, pc.y, pc.z, pc.w, tc.y, tc.z, tc.w);
    }
    {
      const float4 pa = *(const float4*)(p1 + 3 * n0);
      const float4 pb = *(const float4*)(p1 + 3 * n0 + 4);
      const float4 pc = *(const float4*)(p1 + 3 * n0 + 8);
      atomrow(acc[1], w0, pa.x, pa.y, pa.z, ta.x, ta.y, ta.z);
      atomrow(acc[1], w1, pa.w, pb.x, pb.y, ta.w, tb.x, tb.y);
      atomrow(acc[1], w2, pb.z, pb.w, pc.x, tb.z, tb.w, tc.x);
      atomrow(acc[1], w3, pc.y, pc.z, pc.w, tc.y, tc.z, tc.w);
    }
    if (isG0) {  // per-b stats from already-loaded data (32/768 blocks)
      accb[0] += w0 + w1 + w2 + w3;
      accb[1] += w0 * ta.x + w1 * ta.w + w2 * tb.z + w3 * tc.y;
      accb[2] += w0 * ta.y + w1 * tb.x + w2 * tb.w + w3 * tc.z;
      accb[3] += w0 * ta.z + w1 * tb.y + w2 * tc.x + w3 * tc.w;
      accb[4] += w0 * (ta.x * ta.x + ta.y * ta.y + ta.z * ta.z) +
                 w1 * (ta.w * ta.w + tb.x * tb.x + tb.y * tb.y) +
                 w2 * (tb.z * tb.z + tb.w * tb.w + tc.x * tc.x) +
                 w3 * (tc.y * tc.y + tc.z * tc.z + tc.w * tc.w);
      accb[5] += (float)(mk.x + mk.y + mk.z + mk.w);
    }
  }

  // block reduce: 26 (or 32) values
  __shared__ float lds[NW][32];
  const int lane = threadIdx.x & 63;
  const int wave = threadIdx.x >> 6;
#pragma unroll
  for (int sg = 0; sg < SGRP; ++sg)
#pragma unroll
    for (int k = 0; k < 13; ++k) {
      float x = acc[sg][k];
#pragma unroll
      for (int off = 32; off; off >>= 1) x += __shfl_xor(x, off, 64);
      if (lane == 0) lds[wave][sg * 13 + k] = x;
    }
  if (isG0) {
#pragma unroll
    for (int k = 0; k < 6; ++k) {
      float x = accb[k];
#pragma unroll
      for (int off = 32; off; off >>= 1) x += __shfl_xor(x, off, 64);
      if (lane == 0) lds[wave][26 + k] = x;
    }
  }
  __syncthreads();

  const int tid = threadIdx.x;
  const int nvals = isG0 ? 32 : 26;
  if (tid < nvals) {
    float s = 0.f;
#pragma unroll
    for (int w = 0; w < NW; ++w) s += lds[w][tid];
    if (tid < 26) {
      const int sg = tid / 13, j = tid % 13;
      ws[(size_t)((bs0 + sg) * CH + chunk) * 16 + j] = s;
    } else {
      ws[PBOFF + (size_t)(b * CH + chunk) * 8 + (tid - 26)] = s;
    }
  }
}

__global__ __launch_bounds__(NBS) void final_kernel(const float* __restrict__ ws,
                                                    const float* __restrict__ scale,
                                                    float* __restrict__ out) {
  const int tid = threadIdx.x;  // 0..383, tid = bs = b*NS + s
  __shared__ double bv[NB][6];

  if (tid < NB) {
    double s[6] = {0, 0, 0, 0, 0, 0};
    for (int c = 0; c < CH; ++c) {
      const float* q = ws + PBOFF + (tid * CH + c) * 8;
#pragma unroll
      for (int k = 0; k < 6; ++k) s[k] += (double)q[k];
    }
#pragma unroll
    for (int k = 0; k < 6; ++k) bv[tid][k] = s[k];
  }
  __syncthreads();

  const int b = tid / NS;
  double sums[13];
#pragma unroll
  for (int k = 0; k < 13; ++k) sums[k] = 0.0;
  for (int c = 0; c < CH; ++c) {
    const float4* q4 = (const float4*)(ws + (size_t)(tid * CH + c) * 16);
    const float4 qa = q4[0], qb = q4[1], qc = q4[2], qd = q4[3];
    sums[0] += (double)qa.x;  sums[1] += (double)qa.y;
    sums[2] += (double)qa.z;  sums[3] += (double)qa.w;
    sums[4] += (double)qb.x;  sums[5] += (double)qb.y;
    sums[6] += (double)qb.z;  sums[7] += (double)qb.w;
    sums[8] += (double)qc.x;  sums[9] += (double)qc.y;
    sums[10] += (double)qc.z; sums[11] += (double)qc.w;
    sums[12] += (double)qd.x;
  }

  const double wsum = bv[b][0];
  const double St[3] = {bv[b][1], bv[b][2], bv[b][3]};
  const double stt = bv[b][4];
  const double msum = bv[b][5];

  const double spp = sums[0];
  const double Sp[3] = {sums[1], sums[2], sums[3]};
  const double inv = 1.0 / wsum;

  double H[3][3];
#pragma unroll
  for (int i = 0; i < 3; ++i)
#pragma unroll
    for (int j = 0; j < 3; ++j) H[i][j] = sums[4 + 3 * i + j] - Sp[i] * St[j] * inv;

  const double Sq = spp - (Sp[0] * Sp[0] + Sp[1] * Sp[1] + Sp[2] * Sp[2]) * inv;
  const double Sy = stt - (St[0] * St[0] + St[1] * St[1] + St[2] * St[2]) * inv;

  double K[3][3];
#pragma unroll
  for (int i = 0; i < 3; ++i)
#pragma unroll
    for (int j = 0; j < 3; ++j)
      K[i][j] = H[0][i] * H[0][j] + H[1][i] * H[1][j] + H[2][i] * H[2][j];

  const double q = (K[0][0] + K[1][1] + K[2][2]) / 3.0;
  const double p1 = K[0][1] * K[0][1] + K[0][2] * K[0][2] + K[1][2] * K[1][2];
  const double a0 = K[0][0] - q, a1 = K[1][1] - q, a2 = K[2][2] - q;
  const double p2 = a0 * a0 + a1 * a1 + a2 * a2 + 2.0 * p1;
  double e1, e2, e3;
  if (p2 <= 1e-300) {
    e1 = e2 = e3 = q;
  } else {
    const double pp = sqrt(p2 / 6.0);
    const double ip = 1.0 / pp;
    const double B00 = a0 * ip, B11 = a1 * ip, B22 = a2 * ip;
    const double B01 = K[0][1] * ip, B02 = K[0][2] * ip, B12 = K[1][2] * ip;
    double r = 0.5 * (B00 * (B11 * B22 - B12 * B12) - B01 * (B01 * B22 - B12 * B02) +
                      B02 * (B01 * B12 - B11 * B02));
    float rf = fminf(1.0f, fmaxf(-1.0f, (float)r));
    const float phi = acosf(rf) * (1.0f / 3.0f);
    e1 = q + 2.0 * pp * (double)cosf(phi);
    e3 = q + 2.0 * pp * (double)cosf(phi + 2.0943951023931953f);
    e2 = 3.0 * q - e1 - e3;
  }
  const double s1 = sqrt(fmax(e1, 0.0));
  const double s2 = sqrt(fmax(e2, 0.0));
  const double s3 = sqrt(fmax(e3, 0.0));

  const double detH =
      H[0][0] * (H[1][1] * H[2][2] - H[1][2] * H[2][1]) -
      H[0][1] * (H[1][0] * H[2][2] - H[1][2] * H[2][0]) +
      H[0][2] * (H[1][0] * H[2][1] - H[1][1] * H[2][0]);
  const double d = (detH > 0.0) ? 1.0 : ((detH < 0.0) ? -1.0 : 0.0);

  const double cost = Sq + Sy - 2.0 * (s1 + s2 + d * s3);
  double tot = cost / (msum + 1e-6) * (double)scale[tid];
  tot *= 1.0 / (3.0 * (double)NS * (double)NB);

#pragma unroll
  for (int off = 32; off; off >>= 1) tot += __shfl_xor(tot, off, 64);
  __shared__ double red[NBS / 64];
  if ((tid & 63) == 0) red[tid >> 6] = tot;
  __syncthreads();
  if (tid == 0) {
    double s = 0.0;
#pragma unroll
    for (int w = 0; w < NBS / 64; ++w) s += red[w];
    out[0] = (float)s;
  }
}

}  // namespace

extern "C" void kernel_launch(void* const* d_in, const int* in_sizes, int n_in,
                              void* d_out, int out_size, void* d_ws, size_t ws_size,
                              hipStream_t stream) {
  const float* pred = (const float*)d_in[0];
  const float* truec = (const float*)d_in[1];
  const int* mask = (const int*)d_in[2];
  const int* dna = (const int*)d_in[3];
  const int* rna = (const int*)d_in[4];
  const int* lig = (const int*)d_in[5];
  const float* scale = (const float*)d_in[6];
  float* ws = (float*)d_ws;
  float* out = (float*)d_out;

  stats_kernel<<<GRID, TPB, 0, stream>>>(pred, truec, mask, dna, rna, lig, ws);
  final_kernel<<<1, NBS, 0, stream>>>(ws, scale, out);
}